// Round 4
// baseline (1201.903 us; speedup 1.0000x reference)
//
#include <hip/hip_runtime.h>
#include <cstdint>
#include <cstddef>

#define HIDN 2048
#define NROWS 4096   // B*S
#define FFND 8192
#define SEQ 2048
#define QKVN 6144    // packed q|k|v row width

typedef __attribute__((ext_vector_type(8))) __bf16 bf16x8;
typedef __attribute__((ext_vector_type(4))) float f32x4;

__device__ __forceinline__ unsigned short f2b(float f) {
    union { float f; unsigned u; } v; v.f = f;
    unsigned r = v.u + 0x7fffu + ((v.u >> 16) & 1u);
    return (unsigned short)(r >> 16);
}
__device__ __forceinline__ float b2f(unsigned short h) {
    union { unsigned u; float f; } v; v.u = ((unsigned)h) << 16; return v.f;
}
__device__ __forceinline__ void gload16(const void* g, void* lds) {
    __builtin_amdgcn_global_load_lds(
        (const __attribute__((address_space(1))) void*)g,
        (__attribute__((address_space(3))) void*)lds, 16, 0, 0);
}

// ---------------- merged fp32 -> bf16 weight convert (dst contiguous in ws) ----------------
// segments (float4 units): q,k,v,o = 1M each; w1,wg,w2 = 4M each; total 16M
__global__ __launch_bounds__(256) void convall_kernel(
    const float* __restrict__ s0, const float* __restrict__ s1,
    const float* __restrict__ s2, const float* __restrict__ s3,
    const float* __restrict__ s4, const float* __restrict__ s5,
    const float* __restrict__ s6, unsigned short* __restrict__ dst) {
    const int M1 = 1 << 20;
    int i = blockIdx.x * 256 + threadIdx.x;   // < 16M guaranteed by grid
    const float* src; int rel;
    if      (i <  1 * M1) { src = s0; rel = i;          }
    else if (i <  2 * M1) { src = s1; rel = i - 1 * M1; }
    else if (i <  3 * M1) { src = s2; rel = i - 2 * M1; }
    else if (i <  4 * M1) { src = s3; rel = i - 3 * M1; }
    else if (i <  8 * M1) { src = s4; rel = i - 4 * M1; }
    else if (i < 12 * M1) { src = s5; rel = i - 8 * M1; }
    else                  { src = s6; rel = i - 12 * M1; }
    float4 v = ((const float4*)src)[rel];
    ushort4 o;
    o.x = f2b(v.x); o.y = f2b(v.y); o.z = f2b(v.z); o.w = f2b(v.w);
    ((ushort4*)dst)[i] = o;
}

// ---------------- LayerNorm: fp32 in -> bf16 out, one block per 2048-row ----------------
__global__ __launch_bounds__(256) void ln_kernel(const float* __restrict__ x,
                                                 const float* __restrict__ w,
                                                 const float* __restrict__ b,
                                                 unsigned short* __restrict__ out) {
    int row = blockIdx.x, tid = threadIdx.x;
    const float4* xr = (const float4*)(x + (size_t)row * HIDN);
    float4 a0 = xr[tid], a1 = xr[tid + 256];
    float s  = a0.x + a0.y + a0.z + a0.w + a1.x + a1.y + a1.z + a1.w;
    float s2 = a0.x*a0.x + a0.y*a0.y + a0.z*a0.z + a0.w*a0.w
             + a1.x*a1.x + a1.y*a1.y + a1.z*a1.z + a1.w*a1.w;
#pragma unroll
    for (int i = 1; i < 64; i <<= 1) { s += __shfl_xor(s, i); s2 += __shfl_xor(s2, i); }
    __shared__ float red[8];
    if ((tid & 63) == 0) { red[tid >> 6] = s; red[4 + (tid >> 6)] = s2; }
    __syncthreads();
    s  = red[0] + red[1] + red[2] + red[3];
    s2 = red[4] + red[5] + red[6] + red[7];
    float mu  = s * (1.0f / HIDN);
    float var = s2 * (1.0f / HIDN) - mu * mu;
    float rstd = rsqrtf(var + 1e-5f);
    const float4* wv = (const float4*)w;
    const float4* bv = (const float4*)b;
    float4 w0 = wv[tid], w1 = wv[tid + 256], b0 = bv[tid], b1 = bv[tid + 256];
    ushort4 o0, o1;
    o0.x = f2b((a0.x - mu) * rstd * w0.x + b0.x);
    o0.y = f2b((a0.y - mu) * rstd * w0.y + b0.y);
    o0.z = f2b((a0.z - mu) * rstd * w0.z + b0.z);
    o0.w = f2b((a0.w - mu) * rstd * w0.w + b0.w);
    o1.x = f2b((a1.x - mu) * rstd * w1.x + b1.x);
    o1.y = f2b((a1.y - mu) * rstd * w1.y + b1.y);
    o1.z = f2b((a1.z - mu) * rstd * w1.z + b1.z);
    o1.w = f2b((a1.w - mu) * rstd * w1.w + b1.w);
    ushort4* orow = (ushort4*)(out + (size_t)row * HIDN);
    orow[tid] = o0; orow[tid + 256] = o1;
}

// ---------------- GEMM: C[M,N] = A[M,K] @ Bw[N,K]^T  (bf16 in, fp32 acc) ----------------
// 128x128 tile, BK=64 as two BK=32 slabs, 4 waves (2x2 of 64x64), 16x16x32 MFMA.
template <int EPI>
__global__ __launch_bounds__(256)
void gemm_bt(const unsigned short* __restrict__ A, const unsigned short* __restrict__ Bw,
             int M, int N, int K, int tiles_n, float scale,
             const float* __restrict__ bias, const float* __restrict__ resf,
             const unsigned short* __restrict__ aux,
             float* __restrict__ outf, unsigned short* __restrict__ outb) {
    __shared__ unsigned short Asm[2][128 * 32];
    __shared__ unsigned short Bsm[2][128 * 32];
    int tid = threadIdx.x;
    int wave = tid >> 6, lane = tid & 63;
    int lrow = lane & 15, quad = lane >> 4;
    int bm = blockIdx.x / tiles_n, bn = blockIdx.x % tiles_n;
    int wm = (wave >> 1) * 64, wn = (wave & 1) * 64;

    f32x4 acc[4][4];
#pragma unroll
    for (int i = 0; i < 4; i++)
#pragma unroll
        for (int j = 0; j < 4; j++) acc[i][j] = f32x4{0.f, 0.f, 0.f, 0.f};

    int srow = wave * 32 + (lane >> 2);
    int scol = (lane & 3) * 8;
    const unsigned short* Ag = A + (size_t)(bm * 128 + srow) * K + scol;
    const unsigned short* Bg = Bw + (size_t)(bn * 128 + srow) * K + scol;

    for (int k0 = 0; k0 < K; k0 += 64) {
#pragma unroll
        for (int s = 0; s < 2; s++) {
            gload16(Ag + k0 + s * 32, &Asm[s][(wave * 2 + 0) * 512]);
            gload16(Ag + k0 + s * 32 + (size_t)16 * K, &Asm[s][(wave * 2 + 1) * 512]);
            gload16(Bg + k0 + s * 32, &Bsm[s][(wave * 2 + 0) * 512]);
            gload16(Bg + k0 + s * 32 + (size_t)16 * K, &Bsm[s][(wave * 2 + 1) * 512]);
        }
        __syncthreads();
#pragma unroll
        for (int s = 0; s < 2; s++) {
            bf16x8 af[4], bfb[4];
#pragma unroll
            for (int mi = 0; mi < 4; mi++)
                af[mi] = *(const bf16x8*)&Asm[s][(wm + mi * 16 + lrow) * 32 + quad * 8];
#pragma unroll
            for (int ni = 0; ni < 4; ni++)
                bfb[ni] = *(const bf16x8*)&Bsm[s][(wn + ni * 16 + lrow) * 32 + quad * 8];
#pragma unroll
            for (int mi = 0; mi < 4; mi++)
#pragma unroll
                for (int ni = 0; ni < 4; ni++)
                    acc[mi][ni] = __builtin_amdgcn_mfma_f32_16x16x32_bf16(af[mi], bfb[ni], acc[mi][ni], 0, 0, 0);
        }
        __syncthreads();
    }

    int row0 = bm * 128 + wm, col0 = bn * 128 + wn;
#pragma unroll
    for (int mi = 0; mi < 4; mi++) {
#pragma unroll
        for (int ni = 0; ni < 4; ni++) {
            int c = col0 + ni * 16 + lrow;
#pragma unroll
            for (int r = 0; r < 4; r++) {
                int rr = row0 + mi * 16 + quad * 4 + r;
                size_t idx = (size_t)rr * N + c;
                float vv = acc[mi][ni][r];
                if constexpr (EPI == 0) {
                    outb[idx] = f2b(vv * scale);
                } else if constexpr (EPI == 1) {
                    outf[idx] = vv + resf[idx];
                } else if constexpr (EPI == 2) {
                    outb[idx] = f2b(vv + bias[c]);
                } else if constexpr (EPI == 3) {
                    float av = b2f(aux[idx]);
                    float sl = av / (1.f + __expf(-av));
                    outb[idx] = f2b(sl * vv);
                } else if constexpr (EPI == 4) {
                    outf[idx] = vv + bias[c] + resf[idx];
                } else if constexpr (EPI == 5) {
                    outb[idx] = f2b(vv * (c < HIDN ? scale : 1.0f));
                }
            }
        }
    }
}

// ---------------- Flash attention (causal), packed bf16 qkv [B,S,6144], bf16 out ----------------
// BM=128 per block: 4 waves x 32 q-rows (2 m-tiles of 16). BN=64 keys/tile.
// grid: (bh=32, qt16=16 reversed heavy-first) = 512 blocks = 2/CU.
__global__ __launch_bounds__(256)
void attn_kernel(const unsigned short* __restrict__ qkv, unsigned short* __restrict__ o) {
    int bh = blockIdx.x;            // 0..31
    int qt = 15 - blockIdx.y;       // 128-row q-tile, heavy first
    int b = bh >> 4, h = bh & 15;
    int tid = threadIdx.x, wave = tid >> 6, lane = tid & 63;
    int lrow = lane & 15, quad = lane >> 4;
    int q0 = qt * 128;
    size_t base = ((size_t)b * SEQ) * QKVN + h * 128;
    const unsigned short* qp0 = qkv + base;
    const unsigned short* kp0 = qkv + base + HIDN;
    const unsigned short* vp0 = qkv + base + 2 * HIDN;
    size_t obase = ((size_t)b * SEQ) * HIDN + h * 128;

    __shared__ unsigned short Ksm[64 * 136];    // [key][d], pad 128->136
    __shared__ unsigned short VTsm[128 * 72];   // [d][key], pad 64->72
    __shared__ unsigned short Psm[4 * 32 * 72]; // per-wave P tile [32][72]

    // Q fragments: qf[mt][kc], row = q0 + wave*32 + mt*16 + lrow, k = kc*32 + quad*8
    bf16x8 qf[2][4];
#pragma unroll
    for (int mt = 0; mt < 2; mt++) {
        const unsigned short* qp = qp0 + (size_t)(q0 + wave * 32 + mt * 16 + lrow) * QKVN + quad * 8;
#pragma unroll
        for (int kc = 0; kc < 4; kc++) qf[mt][kc] = *(const bf16x8*)(qp + kc * 32);
    }

    f32x4 oacc[2][8];
#pragma unroll
    for (int mt = 0; mt < 2; mt++)
#pragma unroll
        for (int i = 0; i < 8; i++) oacc[mt][i] = f32x4{0.f, 0.f, 0.f, 0.f};
    float m_run[2][4], l_run[2][4];
    int rowg[2][4];
#pragma unroll
    for (int mt = 0; mt < 2; mt++)
#pragma unroll
        for (int r = 0; r < 4; r++) {
            m_run[mt][r] = -1e30f; l_run[mt][r] = 0.f;
            rowg[mt][r] = q0 + wave * 32 + mt * 16 + quad * 4 + r;
        }

    int kt_max = 2 * qt + 1;   // keys up to q0+127
    for (int kt = 0; kt <= kt_max; ++kt) {
        // stage K tile [64][128] -> Ksm
        {
            int r = tid >> 2, cc = (tid & 3) * 32;
            const uint4* src = (const uint4*)(kp0 + (size_t)(kt * 64 + r) * QKVN + cc);
            uint4* dst = (uint4*)&Ksm[r * 136 + cc];
            dst[0] = src[0]; dst[1] = src[1]; dst[2] = src[2]; dst[3] = src[3];
        }
        // stage V tile transposed -> VTsm[d][key]
        {
            int kv = (tid >> 3) * 2, d0 = (tid & 7) * 16;
            const unsigned short* vp = vp0 + (size_t)(kt * 64 + kv) * QKVN + d0;
            unsigned short va[16], vb[16];
            *(uint4*)&va[0] = ((const uint4*)vp)[0];
            *(uint4*)&va[8] = ((const uint4*)vp)[1];
            *(uint4*)&vb[0] = ((const uint4*)(vp + QKVN))[0];
            *(uint4*)&vb[8] = ((const uint4*)(vp + QKVN))[1];
#pragma unroll
            for (int i = 0; i < 16; i++) {
                unsigned pair = (unsigned)va[i] | ((unsigned)vb[i] << 16);
                *(unsigned*)&VTsm[(d0 + i) * 72 + kv] = pair;
            }
        }
        __syncthreads();

        // S = Q K^T for both m-tiles
        f32x4 sacc[2][4];
#pragma unroll
        for (int mt = 0; mt < 2; mt++)
#pragma unroll
            for (int ns = 0; ns < 4; ns++) sacc[mt][ns] = f32x4{0.f, 0.f, 0.f, 0.f};
#pragma unroll
        for (int ns = 0; ns < 4; ns++) {
            const unsigned short* kb = &Ksm[(ns * 16 + lrow) * 136 + quad * 8];
#pragma unroll
            for (int kc = 0; kc < 4; kc++) {
                bf16x8 kf = *(const bf16x8*)(kb + kc * 32);
#pragma unroll
                for (int mt = 0; mt < 2; mt++)
                    sacc[mt][ns] = __builtin_amdgcn_mfma_f32_16x16x32_bf16(qf[mt][kc], kf, sacc[mt][ns], 0, 0, 0);
            }
        }
        // causal mask + online softmax per m-tile
#pragma unroll
        for (int mt = 0; mt < 2; mt++) {
#pragma unroll
            for (int ns = 0; ns < 4; ns++) {
                int colg = kt * 64 + ns * 16 + lrow;
#pragma unroll
                for (int r = 0; r < 4; r++)
                    if (colg > rowg[mt][r]) sacc[mt][ns][r] = -1e30f;
            }
            float mnew[4], alpha[4], rsum[4];
#pragma unroll
            for (int r = 0; r < 4; r++) {
                float mv = fmaxf(fmaxf(sacc[mt][0][r], sacc[mt][1][r]),
                                 fmaxf(sacc[mt][2][r], sacc[mt][3][r]));
#pragma unroll
                for (int off = 1; off < 16; off <<= 1) mv = fmaxf(mv, __shfl_xor(mv, off));
                mnew[r] = fmaxf(m_run[mt][r], mv);
                alpha[r] = __expf(m_run[mt][r] - mnew[r]);
                rsum[r] = 0.f;
            }
#pragma unroll
            for (int ns = 0; ns < 4; ns++)
#pragma unroll
                for (int r = 0; r < 4; r++) {
                    float p = __expf(sacc[mt][ns][r] - mnew[r]);
                    sacc[mt][ns][r] = p;
                    rsum[r] += p;
                }
#pragma unroll
            for (int r = 0; r < 4; r++) {
#pragma unroll
                for (int off = 1; off < 16; off <<= 1) rsum[r] += __shfl_xor(rsum[r], off);
                l_run[mt][r] = l_run[mt][r] * alpha[r] + rsum[r];
                m_run[mt][r] = mnew[r];
            }
#pragma unroll
            for (int nc = 0; nc < 8; nc++)
#pragma unroll
                for (int r = 0; r < 4; r++) oacc[mt][nc][r] *= alpha[r];
        }

        // P: C-layout -> wave-private LDS -> A-layout (no block barrier needed)
        unsigned short* pw = &Psm[wave * 32 * 72];
#pragma unroll
        for (int mt = 0; mt < 2; mt++)
#pragma unroll
            for (int ns = 0; ns < 4; ns++)
#pragma unroll
                for (int r = 0; r < 4; r++)
                    pw[(mt * 16 + quad * 4 + r) * 72 + ns * 16 + lrow] = f2b(sacc[mt][ns][r]);
        asm volatile("s_waitcnt lgkmcnt(0)" ::: "memory");
        bf16x8 pf[2][2];
#pragma unroll
        for (int mt = 0; mt < 2; mt++)
#pragma unroll
            for (int kc = 0; kc < 2; kc++)
                pf[mt][kc] = *(const bf16x8*)&pw[(mt * 16 + lrow) * 72 + kc * 32 + quad * 8];
        // O += P V
#pragma unroll
        for (int nc = 0; nc < 8; nc++)
#pragma unroll
            for (int kc = 0; kc < 2; kc++) {
                bf16x8 vf = *(const bf16x8*)&VTsm[(nc * 16 + lrow) * 72 + kc * 32 + quad * 8];
#pragma unroll
                for (int mt = 0; mt < 2; mt++)
                    oacc[mt][nc] = __builtin_amdgcn_mfma_f32_16x16x32_bf16(pf[mt][kc], vf, oacc[mt][nc], 0, 0, 0);
            }
        __syncthreads();
    }

    // write O
#pragma unroll
    for (int mt = 0; mt < 2; mt++) {
        float inv[4];
#pragma unroll
        for (int r = 0; r < 4; r++) inv[r] = 1.f / l_run[mt][r];
#pragma unroll
        for (int nc = 0; nc < 8; nc++)
#pragma unroll
            for (int r = 0; r < 4; r++) {
                int srow = q0 + wave * 32 + mt * 16 + quad * 4 + r;
                o[obase + (size_t)srow * HIDN + nc * 16 + lrow] = f2b(oacc[mt][nc][r] * inv[r]);
            }
    }
}

// ---------------- launcher ----------------
// Workspace map (peak 224 MB):
//   [0,128)  bf16 weights (one contiguous convert dst):
//            qkv packed 0-24 ([6144,2048]), o 24-32, w1 32-64, wg 64-96, w2 96-128
//   [128,192) a1/ff (in-place SwiGLU) -- aliases hbuf/qkvb (dead by then)
//            hbuf 128-144, qkvb 144-192 ([4096][6144])
//   [192,208) attnb ; [208,224) h2
//   x1 (fp32 residual) lives in d_out (EPI1/EPI4 single-touch RMW-safe).
extern "C" void kernel_launch(void* const* d_in, const int* in_sizes, int n_in,
                              void* d_out, int out_size, void* d_ws, size_t ws_size,
                              hipStream_t stream) {
    const float* x    = (const float*)d_in[0];
    const float* ln1w = (const float*)d_in[2];
    const float* ln1b = (const float*)d_in[3];
    const float* qw   = (const float*)d_in[4];
    const float* kw   = (const float*)d_in[5];
    const float* vw   = (const float*)d_in[6];
    const float* ow   = (const float*)d_in[7];
    const float* ln2w = (const float*)d_in[8];
    const float* ln2b = (const float*)d_in[9];
    const float* w1w  = (const float*)d_in[10];
    const float* w1bias = (const float*)d_in[11];
    const float* wgw  = (const float*)d_in[12];
    const float* w2w  = (const float*)d_in[13];
    const float* w2bias = (const float*)d_in[14];
    float* out = (float*)d_out;

    char* ws = (char*)d_ws;
    const size_t MB = 1ull << 20;
    unsigned short* wall  = (unsigned short*)(ws + 0 * MB);   // 128 MB convert dst
    unsigned short* qkvwb = (unsigned short*)(ws + 0 * MB);
    unsigned short* owb  = (unsigned short*)(ws + 24 * MB);
    unsigned short* w1wb = (unsigned short*)(ws + 32 * MB);
    unsigned short* wgwb = (unsigned short*)(ws + 64 * MB);
    unsigned short* w2wb = (unsigned short*)(ws + 96 * MB);
    unsigned short* a1   = (unsigned short*)(ws + 128 * MB);
    unsigned short* hbuf = (unsigned short*)(ws + 128 * MB);
    unsigned short* qkvb = (unsigned short*)(ws + 144 * MB);
    unsigned short* attnb= (unsigned short*)(ws + 192 * MB);
    unsigned short* h2   = (unsigned short*)(ws + 208 * MB);
    float*          x1   = out;

    // one merged weight convert (16M float4s -> 65536 blocks)
    convall_kernel<<<65536, 256, 0, stream>>>(qw, kw, vw, ow, w1w, wgw, w2w, wall);

    // LN1
    ln_kernel<<<NROWS, 256, 0, stream>>>(x, ln1w, ln1b, hbuf);

    const float qscale = 0.08838834764831845f; // 1/sqrt(128), folded into Q
    // fused QKV projection: [4096,2048] x [6144,2048]^T -> [4096,6144]
    gemm_bt<5><<<dim3(32 * 48), 256, 0, stream>>>(hbuf, qkvwb, NROWS, QKVN, HIDN, 48, qscale,
                                                  nullptr, nullptr, nullptr, nullptr, qkvb);
    // attention
    attn_kernel<<<dim3(32, 16), 256, 0, stream>>>(qkvb, attnb);
    // O-proj + residual -> x1 (fp32, = d_out)
    gemm_bt<1><<<dim3(32 * 16), 256, 0, stream>>>(attnb, owb, NROWS, HIDN, HIDN, 16, 1.0f,
                                                  nullptr, x, nullptr, x1, nullptr);
    // LN2
    ln_kernel<<<NROWS, 256, 0, stream>>>(x1, ln2w, ln2b, h2);
    // FFN: W1+b1 -> a1 ; WG fused silu(a1)*acc -> a1 (in-place) ; W2+b2+res -> out
    gemm_bt<2><<<dim3(32 * 64), 256, 0, stream>>>(h2, w1wb, NROWS, FFND, HIDN, 64, 1.0f,
                                                  w1bias, nullptr, nullptr, nullptr, a1);
    gemm_bt<3><<<dim3(32 * 64), 256, 0, stream>>>(h2, wgwb, NROWS, FFND, HIDN, 64, 1.0f,
                                                  nullptr, nullptr, a1, nullptr, a1);
    gemm_bt<4><<<dim3(32 * 16), 256, 0, stream>>>(a1, w2wb, NROWS, HIDN, FFND, 16, 1.0f,
                                                  w2bias, x1, nullptr, out, nullptr);
    (void)in_sizes; (void)n_in; (void)out_size; (void)ws_size;
}

// Round 5
// 1151.769 us; speedup vs baseline: 1.0435x; 1.0435x over previous
//
#include <hip/hip_runtime.h>
#include <cstdint>
#include <cstddef>

#define HIDN 2048
#define NROWS 4096   // B*S
#define FFND 8192
#define SEQ 2048
#define QKVN 6144    // packed q|k|v row width

typedef __attribute__((ext_vector_type(8))) __bf16 bf16x8;
typedef __attribute__((ext_vector_type(4))) float f32x4;

__device__ __forceinline__ unsigned short f2b(float f) {
    union { float f; unsigned u; } v; v.f = f;
    unsigned r = v.u + 0x7fffu + ((v.u >> 16) & 1u);
    return (unsigned short)(r >> 16);
}
__device__ __forceinline__ float b2f(unsigned short h) {
    union { unsigned u; float f; } v; v.u = ((unsigned)h) << 16; return v.f;
}
__device__ __forceinline__ void gload16(const void* g, void* lds) {
    __builtin_amdgcn_global_load_lds(
        (const __attribute__((address_space(1))) void*)g,
        (__attribute__((address_space(3))) void*)lds, 16, 0, 0);
}

// ---------------- merged fp32 -> bf16 weight convert (dst contiguous in ws) ----------------
__global__ __launch_bounds__(256) void convall_kernel(
    const float* __restrict__ s0, const float* __restrict__ s1,
    const float* __restrict__ s2, const float* __restrict__ s3,
    const float* __restrict__ s4, const float* __restrict__ s5,
    const float* __restrict__ s6, unsigned short* __restrict__ dst) {
    const int M1 = 1 << 20;
    int i = blockIdx.x * 256 + threadIdx.x;   // < 16M guaranteed by grid
    const float* src; int rel;
    if      (i <  1 * M1) { src = s0; rel = i;          }
    else if (i <  2 * M1) { src = s1; rel = i - 1 * M1; }
    else if (i <  3 * M1) { src = s2; rel = i - 2 * M1; }
    else if (i <  4 * M1) { src = s3; rel = i - 3 * M1; }
    else if (i <  8 * M1) { src = s4; rel = i - 4 * M1; }
    else if (i < 12 * M1) { src = s5; rel = i - 8 * M1; }
    else                  { src = s6; rel = i - 12 * M1; }
    float4 v = ((const float4*)src)[rel];
    ushort4 o;
    o.x = f2b(v.x); o.y = f2b(v.y); o.z = f2b(v.z); o.w = f2b(v.w);
    ((ushort4*)dst)[i] = o;
}

// ---------------- LayerNorm: fp32 in -> bf16 out, one block per 2048-row ----------------
__global__ __launch_bounds__(256) void ln_kernel(const float* __restrict__ x,
                                                 const float* __restrict__ w,
                                                 const float* __restrict__ b,
                                                 unsigned short* __restrict__ out) {
    int row = blockIdx.x, tid = threadIdx.x;
    const float4* xr = (const float4*)(x + (size_t)row * HIDN);
    float4 a0 = xr[tid], a1 = xr[tid + 256];
    float s  = a0.x + a0.y + a0.z + a0.w + a1.x + a1.y + a1.z + a1.w;
    float s2 = a0.x*a0.x + a0.y*a0.y + a0.z*a0.z + a0.w*a0.w
             + a1.x*a1.x + a1.y*a1.y + a1.z*a1.z + a1.w*a1.w;
#pragma unroll
    for (int i = 1; i < 64; i <<= 1) { s += __shfl_xor(s, i); s2 += __shfl_xor(s2, i); }
    __shared__ float red[8];
    if ((tid & 63) == 0) { red[tid >> 6] = s; red[4 + (tid >> 6)] = s2; }
    __syncthreads();
    s  = red[0] + red[1] + red[2] + red[3];
    s2 = red[4] + red[5] + red[6] + red[7];
    float mu  = s * (1.0f / HIDN);
    float var = s2 * (1.0f / HIDN) - mu * mu;
    float rstd = rsqrtf(var + 1e-5f);
    const float4* wv = (const float4*)w;
    const float4* bv = (const float4*)b;
    float4 w0 = wv[tid], w1 = wv[tid + 256], b0 = bv[tid], b1 = bv[tid + 256];
    ushort4 o0, o1;
    o0.x = f2b((a0.x - mu) * rstd * w0.x + b0.x);
    o0.y = f2b((a0.y - mu) * rstd * w0.y + b0.y);
    o0.z = f2b((a0.z - mu) * rstd * w0.z + b0.z);
    o0.w = f2b((a0.w - mu) * rstd * w0.w + b0.w);
    o1.x = f2b((a1.x - mu) * rstd * w1.x + b1.x);
    o1.y = f2b((a1.y - mu) * rstd * w1.y + b1.y);
    o1.z = f2b((a1.z - mu) * rstd * w1.z + b1.z);
    o1.w = f2b((a1.w - mu) * rstd * w1.w + b1.w);
    ushort4* orow = (ushort4*)(out + (size_t)row * HIDN);
    orow[tid] = o0; orow[tid + 256] = o1;
}

// ---------------- GEMM: C[M,N] = A[M,K] @ Bw[N,K]^T  (bf16 in, fp32 acc) ----------------
// 128x128 tile, BK=64 as two BK=32 slabs, 4 waves (2x2 of 64x64), 16x16x32 MFMA.
// XCD-aware swizzle: xcd = id&7 owns bn-chunk [xcd*tiles_n/8, ..+tiles_n/8) so its
// B working set (~4 MB for FFN) stays L2-resident -> shorter vmcnt(0) barrier drains.
// Requires tiles_n % 8 == 0 and grid % 8 == 0.
template <int EPI>
__global__ __launch_bounds__(256)
void gemm_bt(const unsigned short* __restrict__ A, const unsigned short* __restrict__ Bw,
             int M, int N, int K, int tiles_n, float scale,
             const float* __restrict__ bias, const float* __restrict__ resf,
             const unsigned short* __restrict__ aux,
             float* __restrict__ outf, unsigned short* __restrict__ outb) {
    __shared__ unsigned short Asm[2][128 * 32];
    __shared__ unsigned short Bsm[2][128 * 32];
    int tid = threadIdx.x;
    int wave = tid >> 6, lane = tid & 63;
    int lrow = lane & 15, quad = lane >> 4;
    int nchunk = tiles_n >> 3;
    int xcd = blockIdx.x & 7;
    int pxi = blockIdx.x >> 3;
    int bn = xcd * nchunk + pxi % nchunk;
    int bm = pxi / nchunk;
    int wm = (wave >> 1) * 64, wn = (wave & 1) * 64;

    f32x4 acc[4][4];
#pragma unroll
    for (int i = 0; i < 4; i++)
#pragma unroll
        for (int j = 0; j < 4; j++) acc[i][j] = f32x4{0.f, 0.f, 0.f, 0.f};

    int srow = wave * 32 + (lane >> 2);
    int scol = (lane & 3) * 8;
    const unsigned short* Ag = A + (size_t)(bm * 128 + srow) * K + scol;
    const unsigned short* Bg = Bw + (size_t)(bn * 128 + srow) * K + scol;

    for (int k0 = 0; k0 < K; k0 += 64) {
#pragma unroll
        for (int s = 0; s < 2; s++) {
            gload16(Ag + k0 + s * 32, &Asm[s][(wave * 2 + 0) * 512]);
            gload16(Ag + k0 + s * 32 + (size_t)16 * K, &Asm[s][(wave * 2 + 1) * 512]);
            gload16(Bg + k0 + s * 32, &Bsm[s][(wave * 2 + 0) * 512]);
            gload16(Bg + k0 + s * 32 + (size_t)16 * K, &Bsm[s][(wave * 2 + 1) * 512]);
        }
        __syncthreads();
#pragma unroll
        for (int s = 0; s < 2; s++) {
            bf16x8 af[4], bfb[4];
#pragma unroll
            for (int mi = 0; mi < 4; mi++)
                af[mi] = *(const bf16x8*)&Asm[s][(wm + mi * 16 + lrow) * 32 + quad * 8];
#pragma unroll
            for (int ni = 0; ni < 4; ni++)
                bfb[ni] = *(const bf16x8*)&Bsm[s][(wn + ni * 16 + lrow) * 32 + quad * 8];
#pragma unroll
            for (int mi = 0; mi < 4; mi++)
#pragma unroll
                for (int ni = 0; ni < 4; ni++)
                    acc[mi][ni] = __builtin_amdgcn_mfma_f32_16x16x32_bf16(af[mi], bfb[ni], acc[mi][ni], 0, 0, 0);
        }
        __syncthreads();
    }

    int row0 = bm * 128 + wm, col0 = bn * 128 + wn;
#pragma unroll
    for (int mi = 0; mi < 4; mi++) {
#pragma unroll
        for (int ni = 0; ni < 4; ni++) {
            int c = col0 + ni * 16 + lrow;
#pragma unroll
            for (int r = 0; r < 4; r++) {
                int rr = row0 + mi * 16 + quad * 4 + r;
                size_t idx = (size_t)rr * N + c;
                float vv = acc[mi][ni][r];
                if constexpr (EPI == 0) {
                    outb[idx] = f2b(vv * scale);
                } else if constexpr (EPI == 1) {
                    outf[idx] = vv + resf[idx];
                } else if constexpr (EPI == 2) {
                    outb[idx] = f2b(vv + bias[c]);
                } else if constexpr (EPI == 3) {
                    float av = b2f(aux[idx]);
                    float sl = av / (1.f + __expf(-av));
                    outb[idx] = f2b(sl * vv);
                } else if constexpr (EPI == 4) {
                    outf[idx] = vv + bias[c] + resf[idx];
                } else if constexpr (EPI == 5) {
                    outb[idx] = f2b(vv * (c < HIDN ? scale : 1.0f));
                }
            }
        }
    }
}

// ---------------- Flash attention (causal), packed bf16 qkv [B,S,6144], bf16 out ----------------
// BM=64 (critical-path-optimal), BN=64. grid (bh=32, qt=32 reversed heavy-first).
// 2 barriers/tile: P roundtrip through wave-private LDS needs only lgkmcnt(0).
__global__ __launch_bounds__(256)
void attn_kernel(const unsigned short* __restrict__ qkv, unsigned short* __restrict__ o) {
    int bh = blockIdx.x;            // 0..31
    int qt = 31 - blockIdx.y;       // heavy tiles first
    int b = bh >> 4, h = bh & 15;
    int tid = threadIdx.x, wave = tid >> 6, lane = tid & 63;
    int lrow = lane & 15, quad = lane >> 4;
    int q0 = qt * 64;
    size_t base = ((size_t)b * SEQ) * QKVN + h * 128;
    const unsigned short* qp0 = qkv + base;
    const unsigned short* kp0 = qkv + base + HIDN;
    const unsigned short* vp0 = qkv + base + 2 * HIDN;
    size_t obase = ((size_t)b * SEQ) * HIDN + h * 128;

    __shared__ unsigned short Ksm[64 * 136];    // [key][d], pad 128->136
    __shared__ unsigned short VTsm[128 * 72];   // [d][key], pad 64->72
    __shared__ unsigned short Psm[4 * 16 * 72]; // per-wave P tile [16][72]

    bf16x8 qf[4];
    {
        const unsigned short* qp = qp0 + (size_t)(q0 + wave * 16 + lrow) * QKVN + quad * 8;
#pragma unroll
        for (int kc = 0; kc < 4; kc++) qf[kc] = *(const bf16x8*)(qp + kc * 32);
    }

    f32x4 oacc[8];
#pragma unroll
    for (int i = 0; i < 8; i++) oacc[i] = f32x4{0.f, 0.f, 0.f, 0.f};
    float m_run[4], l_run[4];
    int rowg[4];
#pragma unroll
    for (int r = 0; r < 4; r++) {
        m_run[r] = -1e30f; l_run[r] = 0.f;
        rowg[r] = q0 + wave * 16 + quad * 4 + r;
    }

    for (int kt = 0; kt <= qt; ++kt) {
        // stage K tile [64][128] -> Ksm
        {
            int r = tid >> 2, cc = (tid & 3) * 32;
            const uint4* src = (const uint4*)(kp0 + (size_t)(kt * 64 + r) * QKVN + cc);
            uint4* dst = (uint4*)&Ksm[r * 136 + cc];
            dst[0] = src[0]; dst[1] = src[1]; dst[2] = src[2]; dst[3] = src[3];
        }
        // stage V tile transposed -> VTsm[d][key]
        {
            int kv = (tid >> 3) * 2, d0 = (tid & 7) * 16;
            const unsigned short* vp = vp0 + (size_t)(kt * 64 + kv) * QKVN + d0;
            unsigned short va[16], vb[16];
            *(uint4*)&va[0] = ((const uint4*)vp)[0];
            *(uint4*)&va[8] = ((const uint4*)vp)[1];
            *(uint4*)&vb[0] = ((const uint4*)(vp + QKVN))[0];
            *(uint4*)&vb[8] = ((const uint4*)(vp + QKVN))[1];
#pragma unroll
            for (int i = 0; i < 16; i++) {
                unsigned pair = (unsigned)va[i] | ((unsigned)vb[i] << 16);
                *(unsigned*)&VTsm[(d0 + i) * 72 + kv] = pair;
            }
        }
        __syncthreads();

        // S = Q K^T  (scale pre-folded into q)
        f32x4 sacc[4];
#pragma unroll
        for (int ns = 0; ns < 4; ns++) sacc[ns] = f32x4{0.f, 0.f, 0.f, 0.f};
#pragma unroll
        for (int ns = 0; ns < 4; ns++) {
            const unsigned short* kb = &Ksm[(ns * 16 + lrow) * 136 + quad * 8];
#pragma unroll
            for (int kc = 0; kc < 4; kc++) {
                bf16x8 kf = *(const bf16x8*)(kb + kc * 32);
                sacc[ns] = __builtin_amdgcn_mfma_f32_16x16x32_bf16(qf[kc], kf, sacc[ns], 0, 0, 0);
            }
        }
        // causal mask
#pragma unroll
        for (int ns = 0; ns < 4; ns++) {
            int colg = kt * 64 + ns * 16 + lrow;
#pragma unroll
            for (int r = 0; r < 4; r++)
                if (colg > rowg[r]) sacc[ns][r] = -1e30f;
        }
        // online softmax
        float mnew[4], alpha[4], rsum[4];
#pragma unroll
        for (int r = 0; r < 4; r++) {
            float mv = fmaxf(fmaxf(sacc[0][r], sacc[1][r]), fmaxf(sacc[2][r], sacc[3][r]));
#pragma unroll
            for (int off = 1; off < 16; off <<= 1) mv = fmaxf(mv, __shfl_xor(mv, off));
            mnew[r] = fmaxf(m_run[r], mv);
            alpha[r] = __expf(m_run[r] - mnew[r]);
            rsum[r] = 0.f;
        }
#pragma unroll
        for (int ns = 0; ns < 4; ns++)
#pragma unroll
            for (int r = 0; r < 4; r++) {
                float p = __expf(sacc[ns][r] - mnew[r]);
                sacc[ns][r] = p;
                rsum[r] += p;
            }
#pragma unroll
        for (int r = 0; r < 4; r++) {
#pragma unroll
            for (int off = 1; off < 16; off <<= 1) rsum[r] += __shfl_xor(rsum[r], off);
            l_run[r] = l_run[r] * alpha[r] + rsum[r];
            m_run[r] = mnew[r];
        }
#pragma unroll
        for (int nc = 0; nc < 8; nc++)
#pragma unroll
            for (int r = 0; r < 4; r++) oacc[nc][r] *= alpha[r];

        // P: C-layout -> wave-private LDS -> A-layout (lgkmcnt only, no block barrier)
        unsigned short* pw = &Psm[wave * 16 * 72];
#pragma unroll
        for (int ns = 0; ns < 4; ns++)
#pragma unroll
            for (int r = 0; r < 4; r++)
                pw[(quad * 4 + r) * 72 + ns * 16 + lrow] = f2b(sacc[ns][r]);
        asm volatile("s_waitcnt lgkmcnt(0)" ::: "memory");
        bf16x8 pf[2];
#pragma unroll
        for (int kc = 0; kc < 2; kc++)
            pf[kc] = *(const bf16x8*)&pw[lrow * 72 + kc * 32 + quad * 8];
        // O += P V
#pragma unroll
        for (int nc = 0; nc < 8; nc++) {
#pragma unroll
            for (int kc = 0; kc < 2; kc++) {
                bf16x8 vf = *(const bf16x8*)&VTsm[(nc * 16 + lrow) * 72 + kc * 32 + quad * 8];
                oacc[nc] = __builtin_amdgcn_mfma_f32_16x16x32_bf16(pf[kc], vf, oacc[nc], 0, 0, 0);
            }
        }
        __syncthreads();
    }

    // write O
    float inv[4];
#pragma unroll
    for (int r = 0; r < 4; r++) inv[r] = 1.f / l_run[r];
#pragma unroll
    for (int nc = 0; nc < 8; nc++) {
#pragma unroll
        for (int r = 0; r < 4; r++) {
            int srow = q0 + wave * 16 + quad * 4 + r;
            o[obase + (size_t)srow * HIDN + nc * 16 + lrow] = f2b(oacc[nc][r] * inv[r]);
        }
    }
}

// ---------------- launcher ----------------
// Workspace map (peak 224 MB):
//   [0,128)  bf16 weights (one contiguous convert dst):
//            qkv packed 0-24 ([6144,2048]), o 24-32, w1 32-64, wg 64-96, w2 96-128
//   [128,192) a1/ff (in-place SwiGLU) -- aliases hbuf/qkvb (dead by then)
//            hbuf 128-144, qkvb 144-192 ([4096][6144])
//   [192,208) attnb ; [208,224) h2
//   x1 (fp32 residual) lives in d_out (EPI1/EPI4 single-touch RMW-safe).
extern "C" void kernel_launch(void* const* d_in, const int* in_sizes, int n_in,
                              void* d_out, int out_size, void* d_ws, size_t ws_size,
                              hipStream_t stream) {
    const float* x    = (const float*)d_in[0];
    const float* ln1w = (const float*)d_in[2];
    const float* ln1b = (const float*)d_in[3];
    const float* qw   = (const float*)d_in[4];
    const float* kw   = (const float*)d_in[5];
    const float* vw   = (const float*)d_in[6];
    const float* ow   = (const float*)d_in[7];
    const float* ln2w = (const float*)d_in[8];
    const float* ln2b = (const float*)d_in[9];
    const float* w1w  = (const float*)d_in[10];
    const float* w1bias = (const float*)d_in[11];
    const float* wgw  = (const float*)d_in[12];
    const float* w2w  = (const float*)d_in[13];
    const float* w2bias = (const float*)d_in[14];
    float* out = (float*)d_out;

    char* ws = (char*)d_ws;
    const size_t MB = 1ull << 20;
    unsigned short* wall  = (unsigned short*)(ws + 0 * MB);
    unsigned short* qkvwb = (unsigned short*)(ws + 0 * MB);
    unsigned short* owb  = (unsigned short*)(ws + 24 * MB);
    unsigned short* w1wb = (unsigned short*)(ws + 32 * MB);
    unsigned short* wgwb = (unsigned short*)(ws + 64 * MB);
    unsigned short* w2wb = (unsigned short*)(ws + 96 * MB);
    unsigned short* a1   = (unsigned short*)(ws + 128 * MB);
    unsigned short* hbuf = (unsigned short*)(ws + 128 * MB);
    unsigned short* qkvb = (unsigned short*)(ws + 144 * MB);
    unsigned short* attnb= (unsigned short*)(ws + 192 * MB);
    unsigned short* h2   = (unsigned short*)(ws + 208 * MB);
    float*          x1   = out;

    // one merged weight convert (16M float4s)
    convall_kernel<<<65536, 256, 0, stream>>>(qw, kw, vw, ow, w1w, wgw, w2w, wall);

    // LN1
    ln_kernel<<<NROWS, 256, 0, stream>>>(x, ln1w, ln1b, hbuf);

    const float qscale = 0.08838834764831845f; // 1/sqrt(128), folded into Q
    // fused QKV projection: [4096,2048] x [6144,2048]^T -> [4096,6144]
    gemm_bt<5><<<dim3(32 * 48), 256, 0, stream>>>(hbuf, qkvwb, NROWS, QKVN, HIDN, 48, qscale,
                                                  nullptr, nullptr, nullptr, nullptr, qkvb);
    // attention
    attn_kernel<<<dim3(32, 32), 256, 0, stream>>>(qkvb, attnb);
    // O-proj + residual -> x1 (fp32, = d_out)
    gemm_bt<1><<<dim3(32 * 16), 256, 0, stream>>>(attnb, owb, NROWS, HIDN, HIDN, 16, 1.0f,
                                                  nullptr, x, nullptr, x1, nullptr);
    // LN2
    ln_kernel<<<NROWS, 256, 0, stream>>>(x1, ln2w, ln2b, h2);
    // FFN: W1+b1 -> a1 ; WG fused silu(a1)*acc -> a1 (in-place) ; W2+b2+res -> out
    gemm_bt<2><<<dim3(32 * 64), 256, 0, stream>>>(h2, w1wb, NROWS, FFND, HIDN, 64, 1.0f,
                                                  w1bias, nullptr, nullptr, nullptr, a1);
    gemm_bt<3><<<dim3(32 * 64), 256, 0, stream>>>(h2, wgwb, NROWS, FFND, HIDN, 64, 1.0f,
                                                  nullptr, nullptr, a1, nullptr, a1);
    gemm_bt<4><<<dim3(32 * 16), 256, 0, stream>>>(a1, w2wb, NROWS, HIDN, FFND, 16, 1.0f,
                                                  w2bias, x1, nullptr, out, nullptr);
    (void)in_sizes; (void)n_in; (void)out_size; (void)ws_size;
}